// Round 5
// baseline (830.691 us; speedup 1.0000x reference)
//
#include <hip/hip_runtime.h>
#include <math.h>

#define T_TOK 4096
#define HD    2048
#define NEXP  32
#define IR    1408
#define ISH   2816
#define NPAIR (T_TOK*4)
#define SRK   136      // padded bf16 row stride (cold helper paths only)
#define MTILES 11      // I-tiles (of 64) per z-chunk: routed z=2, shared z=4

typedef unsigned short ushort_t;
typedef __attribute__((ext_vector_type(8))) short    short8;
typedef __attribute__((ext_vector_type(8))) __bf16   bf16x8;
typedef __attribute__((ext_vector_type(4))) float    f32x4;

__device__ __forceinline__ f32x4 MF(short8 a, short8 b, f32x4 c) {
  return __builtin_amdgcn_mfma_f32_16x16x32_bf16(
      __builtin_bit_cast(bf16x8, a), __builtin_bit_cast(bf16x8, b), c, 0, 0, 0);
}
__device__ __forceinline__ ushort_t f2b(float f) {
  unsigned u = __float_as_uint(f);
  unsigned r = (u + 0x7fffu + ((u >> 16) & 1u)) >> 16;   // RNE
  return (ushort_t)r;
}
__device__ __forceinline__ ushort4 pk4(f32x4 v) {
  ushort4 o; o.x=f2b(v[0]); o.y=f2b(v[1]); o.z=f2b(v[2]); o.w=f2b(v[3]); return o;
}
__device__ __forceinline__ float b2f(ushort_t u) {
  return __uint_as_float(((unsigned)u) << 16);
}

// async global->LDS 16B; LDS dst wave-uniform base (+lane*16 implicit)
__device__ __forceinline__ void gll16(const ushort_t* g, ushort_t* l) {
  __builtin_amdgcn_global_load_lds(
      (const __attribute__((address_space(1))) unsigned int*)(const void*)g,
      (__attribute__((address_space(3))) unsigned int*)(void*)l, 16, 0, 0);
}

// ---- swizzled tile loaders (phys 16B-granule = logical ^ (row&mask)) ----
__device__ __forceinline__ void load_64x128_swz(
    const ushort_t* __restrict__ g, size_t gstride, ushort_t* lds, int tid)
{
  const int lane = tid & 63, w = tid >> 6;
  #pragma unroll
  for (int s = 0; s < 4; ++s) {
    int rbase = s*16 + w*4;
    int r = rbase + (lane >> 4);
    int p = lane & 15;
    gll16(g + (size_t)r*gstride + ((p ^ (r & 15)) << 3), lds + rbase*128);
  }
}
__device__ __forceinline__ void load_128x64_swz(
    const ushort_t* __restrict__ g, size_t gstride, ushort_t* lds, int tid)
{
  const int lane = tid & 63, w = tid >> 6;
  #pragma unroll
  for (int s = 0; s < 4; ++s) {
    int rbase = s*32 + w*8;
    int r = rbase + (lane >> 3);
    int p = lane & 7;
    gll16(g + (size_t)r*gstride + ((p ^ (r & 7)) << 3), lds + rbase*64);
  }
}

// ---------------------------------------------------------------- fused cvt
#define NSEG 19
struct CvtSegs {
  const float* s[NSEG];
  ushort_t* d[NSEG];
  int n4[NSEG];
  int blk0[NSEG+1];
};
__global__ __launch_bounds__(256) void cvt_all_kernel(CvtSegs cs)
{
  int b = blockIdx.x;
  int k = 0;
  #pragma unroll 1
  while (k+1 < NSEG && b >= cs.blk0[k+1]) ++k;
  int i = (b - cs.blk0[k])*256 + threadIdx.x;
  if (i < cs.n4[k]) {
    float4 v = ((const float4*)cs.s[k])[i];
    ushort4 o; o.x=f2b(v.x); o.y=f2b(v.y); o.z=f2b(v.z); o.w=f2b(v.w);
    ((ushort4*)cs.d[k])[i] = o;
  }
}

// ---------------------------------------------------------------- gate (fp32 — selection must stay accurate)
__global__ __launch_bounds__(256) void gate_kernel(
    const float* __restrict__ x, const float* __restrict__ gw,
    int* __restrict__ topk_idx, float* __restrict__ topk_w, int* __restrict__ cnt)
{
  __shared__ float gws[32*132];
  __shared__ float xs[4*132];
  const int tid = threadIdx.x;
  const int w = tid >> 6, lane = tid & 63;
  const int t0 = blockIdx.x * 4;
  const int e = lane & 31, half = lane >> 5;

  float acc = 0.f;
  for (int ck = 0; ck < HD/128; ++ck) {
    for (int li = tid; li < 1024; li += 256) {
      int r = li >> 5, c4 = li & 31;
      *(float4*)(gws + r*132 + c4*4) = *(const float4*)(gw + (size_t)r*HD + ck*128 + c4*4);
    }
    for (int li = tid; li < 128; li += 256) {
      int r = li >> 5, c4 = li & 31;
      *(float4*)(xs + r*132 + c4*4) = *(const float4*)(x + (size_t)(t0+r)*HD + ck*128 + c4*4);
    }
    __syncthreads();
    #pragma unroll
    for (int k4 = 0; k4 < 16; ++k4) {
      float4 xv = *(const float4*)(xs + w*132 + half*64 + k4*4);
      float4 wv = *(const float4*)(gws + e*132 + half*64 + k4*4);
      acc += xv.x*wv.x + xv.y*wv.y + xv.z*wv.z + xv.w*wv.w;
    }
    __syncthreads();
  }
  float p = acc;
  p += __shfl_down(p, 32);
  float logit = (lane < 32) ? p : -INFINITY;
  float m = logit;
  #pragma unroll
  for (int o = 32; o >= 1; o >>= 1) m = fmaxf(m, __shfl_xor(m, o));
  float ex = (lane < 32) ? expf(logit - m) : 0.f;
  float se = ex;
  #pragma unroll
  for (int o = 32; o >= 1; o >>= 1) se += __shfl_xor(se, o);
  float score = ex / se;

  bool taken = false;
  float selw[4]; int seli[4];
  for (int k = 0; k < 4; ++k) {
    float cur = (lane < 32 && !taken) ? score : -1.f;
    float mm = cur;
    #pragma unroll
    for (int o = 32; o >= 1; o >>= 1) mm = fmaxf(mm, __shfl_xor(mm, o));
    unsigned long long b = __ballot(cur == mm);
    int il = __ffsll(b) - 1;
    if (lane == il) taken = true;
    selw[k] = mm; seli[k] = il;
  }
  float wsum = selw[0]+selw[1]+selw[2]+selw[3] + 1e-20f;
  int t = t0 + w;
  if (lane < 4) {
    topk_idx[t*4+lane] = seli[lane];
    topk_w[t*4+lane]  = selw[lane] / wsum;
    atomicAdd(&cnt[seli[lane]], 1);
  }
}

__global__ void scan_kernel(const int* __restrict__ cnt, int* __restrict__ offA)
{
  if (threadIdx.x == 0) {
    int a = 0;
    for (int e = 0; e < NEXP; ++e) { offA[e] = a; a += cnt[e]; }
    offA[NEXP] = a;
  }
}

__global__ __launch_bounds__(256) void scatter_kernel(
    const int* __restrict__ topk_idx, const float* __restrict__ topk_w,
    const int* __restrict__ offA, int* __restrict__ fill,
    int* __restrict__ list_tok, float* __restrict__ list_w, int* __restrict__ slot_of)
{
  int t = blockIdx.x*256 + threadIdx.x;
  if (t >= T_TOK) return;
  #pragma unroll
  for (int k = 0; k < 4; ++k) {
    int e = topk_idx[t*4+k];
    int pos = atomicAdd(&fill[e], 1);
    int s = offA[e] + pos;
    list_tok[s] = t;
    list_w[s]  = topk_w[t*4+k];
    slot_of[t*4+k] = s;
  }
}

// ------------------------------------------------- R projections
__global__ __launch_bounds__(256) void rproj_kernel(
    const ushort_t* __restrict__ xb,
    const ushort_t* __restrict__ Rg, const ushort_t* __restrict__ Ru,
    const ushort_t* __restrict__ sRg, const ushort_t* __restrict__ sRu,
    ushort_t* __restrict__ rg, ushort_t* __restrict__ ru,
    ushort_t* __restrict__ sa, ushort_t* __restrict__ su)
{
  __shared__ ushort_t abuf[2][64*128];
  const ushort_t* W; ushort_t* Y;
  switch (blockIdx.y) {
    case 0:  W = Rg;  Y = rg; break;
    case 1:  W = Ru;  Y = ru; break;
    case 2:  W = sRg; Y = sa; break;
    default: W = sRu; Y = su; break;
  }
  const int tid = threadIdx.x;
  const int lane = tid & 63, ln = lane & 15, q = lane >> 4;
  const int wv = tid >> 6, mh = wv >> 1, nh = wv & 1;
  const int r0 = blockIdx.x * 64;

  f32x4 acc[2][4];
  #pragma unroll
  for (int i = 0; i < 2; ++i)
    #pragma unroll
    for (int j = 0; j < 4; ++j) acc[i][j] = (f32x4){0.f,0.f,0.f,0.f};

  load_64x128_swz(xb + (size_t)r0*HD, HD, abuf[0], tid);
  for (int kt = 0; kt < 16; ++kt) {
    __syncthreads();
    if (kt+1 < 16)
      load_64x128_swz(xb + (size_t)r0*HD + (kt+1)*128, HD, abuf[(kt+1)&1], tid);
    const ushort_t* A = abuf[kt&1];
    #pragma unroll
    for (int c = 0; c < 4; ++c) {
      short8 a[2], b[4];
      #pragma unroll
      for (int i = 0; i < 2; ++i) {
        int rr = mh*32 + i*16 + ln;
        a[i] = *(const short8*)(A + rr*128 + (((c*4+q) ^ (rr&15)) << 3));
      }
      #pragma unroll
      for (int j = 0; j < 4; ++j)
        b[j] = *(const short8*)(W + (size_t)(nh*64 + j*16 + ln)*HD + kt*128 + c*32 + q*8);
      #pragma unroll
      for (int i = 0; i < 2; ++i)
        #pragma unroll
        for (int j = 0; j < 4; ++j) acc[i][j] = MF(a[i], b[j], acc[i][j]);
    }
  }
  #pragma unroll
  for (int i = 0; i < 2; ++i)
    #pragma unroll
    for (int j = 0; j < 4; ++j)
      #pragma unroll
      for (int r = 0; r < 4; ++r)
        Y[(size_t)(r0 + mh*32 + i*16 + q*4 + r)*128 + nh*64 + j*16 + ln] = f2b(acc[i][j][r]);
}

// -------- cold helper (pair_proj): acc = A_lds[64][SRK] @ Wg[128][128]^T
__device__ __forceinline__ void gemm64x128_regs(
    int tid, const ushort_t* __restrict__ A, const ushort_t* __restrict__ Wg,
    ushort_t* __restrict__ stage, f32x4 acc[2][2][2])
{
  const int lane = tid & 63, ln = lane & 15, q = lane >> 4;
  const int wv = tid >> 6, mh = wv >> 1, nh = wv & 1;
  #pragma unroll
  for (int h = 0; h < 2; ++h)
    #pragma unroll
    for (int i = 0; i < 2; ++i)
      #pragma unroll
      for (int j = 0; j < 2; ++j) acc[h][i][j] = (f32x4){0.f,0.f,0.f,0.f};
  for (int h = 0; h < 2; ++h) {
    for (int li = tid; li < 64*16; li += 256) {
      int r = li >> 4, c = (li & 15) << 3;
      *(short8*)(stage + r*SRK + c) = *(const short8*)(Wg + (size_t)(h*64 + r)*128 + c);
    }
    __syncthreads();
    #pragma unroll
    for (int c = 0; c < 4; ++c) {
      short8 a[2], b[2];
      #pragma unroll
      for (int i = 0; i < 2; ++i)
        a[i] = *(const short8*)(A + (mh*32 + i*16 + ln)*SRK + c*32 + q*8);
      #pragma unroll
      for (int j = 0; j < 2; ++j)
        b[j] = *(const short8*)(stage + (nh*32 + j*16 + ln)*SRK + c*32 + q*8);
      #pragma unroll
      for (int i = 0; i < 2; ++i)
        #pragma unroll
        for (int j = 0; j < 2; ++j) acc[h][i][j] = MF(a[i], b[j], acc[h][i][j]);
    }
    __syncthreads();
  }
}

// ---------------------------------------------------------------- pair_proj
__global__ __launch_bounds__(256) void pair_proj_kernel(
    const ushort_t* __restrict__ rgb, const ushort_t* __restrict__ rub,
    const ushort_t* __restrict__ sab, const ushort_t* __restrict__ sub,
    const ushort_t* __restrict__ Ug, const ushort_t* __restrict__ Uu,
    const ushort_t* __restrict__ sUg, const ushort_t* __restrict__ sUu,
    const int* __restrict__ offA, const int* __restrict__ cntA,
    const int* __restrict__ list_tok,
    ushort_t* __restrict__ t1R, ushort_t* __restrict__ t2R,
    ushort_t* __restrict__ t1S, ushort_t* __restrict__ t2S)
{
  __shared__ ushort_t ldsX[64*SRK];
  __shared__ ushort_t stage[64*SRK];
  __shared__ int toks[64];
  const int tid = threadIdx.x;
  const int by = blockIdx.y;
  const bool shm = (by == NEXP);
  const int nrows = shm ? T_TOK : cntA[by];
  const int s0 = blockIdx.x * 64;
  if (s0 >= nrows) return;
  const int base = shm ? 0 : offA[by];
  const ushort_t* pUg = shm ? sUg : Ug + (size_t)by*128*128;
  const ushort_t* pUu = shm ? sUu : Uu + (size_t)by*128*128;
  const int lane = tid & 63, ln = lane & 15, q = lane >> 4;
  const int wv = tid >> 6, mh = wv >> 1, nh = wv & 1;

  if (tid < 64) {
    int sc = s0 + tid; if (sc > nrows-1) sc = nrows-1;
    toks[tid] = shm ? sc : list_tok[base + sc];
  }
  __syncthreads();

  f32x4 acc[2][2][2];
  for (int li = tid; li < 64*16; li += 256) {
    int r = li >> 4, c = (li & 15) << 3;
    const ushort_t* src = shm ? sab : rgb;
    *(short8*)(ldsX + r*SRK + c) = *(const short8*)(src + (size_t)toks[r]*128 + c);
  }
  __syncthreads();
  gemm64x128_regs(tid, ldsX, pUg, stage, acc);
  {
    ushort_t* dst = shm ? t1S : (t1R + (size_t)base*128);
    #pragma unroll
    for (int h = 0; h < 2; ++h)
      #pragma unroll
      for (int i = 0; i < 2; ++i)
        #pragma unroll
        for (int r = 0; r < 4; ++r) {
          int gs = s0 + mh*32 + i*16 + q*4 + r;
          if (gs < nrows) {
            #pragma unroll
            for (int j = 0; j < 2; ++j)
              dst[(size_t)gs*128 + h*64 + nh*32 + j*16 + ln] = f2b(acc[h][i][j][r]);
          }
        }
  }
  for (int li = tid; li < 64*16; li += 256) {
    int r = li >> 4, c = (li & 15) << 3;
    const ushort_t* src = shm ? sub : rub;
    *(short8*)(ldsX + r*SRK + c) = *(const short8*)(src + (size_t)toks[r]*128 + c);
  }
  __syncthreads();
  gemm64x128_regs(tid, ldsX, pUu, stage, acc);
  {
    ushort_t* dst = shm ? t2S : (t2R + (size_t)base*128);
    #pragma unroll
    for (int h = 0; h < 2; ++h)
      #pragma unroll
      for (int i = 0; i < 2; ++i)
        #pragma unroll
        for (int r = 0; r < 4; ++r) {
          int gs = s0 + mh*32 + i*16 + q*4 + r;
          if (gs < nrows) {
            #pragma unroll
            for (int j = 0; j < 2; ++j)
              dst[(size_t)gs*128 + h*64 + nh*32 + j*16 + ln] = f2b(acc[h][i][j][r]);
          }
        }
  }
}

// ---------------------------------------------------------------- mid
// M=128 rows/block, grid (32, 33, 4). Operand-swapped MFMA.
__global__ __launch_bounds__(256, 2) void mid_kernel(
    const ushort_t* __restrict__ t1R, const ushort_t* __restrict__ t2R,
    const ushort_t* __restrict__ t1S, const ushort_t* __restrict__ t2S,
    const ushort_t* __restrict__ Cg, const ushort_t* __restrict__ Cu,
    const ushort_t* __restrict__ Rd,
    const ushort_t* __restrict__ sCg, const ushort_t* __restrict__ sCu,
    const ushort_t* __restrict__ sRd,
    const int* __restrict__ offA, const int* __restrict__ cntA,
    float* __restrict__ rdRp, float* __restrict__ rdSp)
{
  __shared__ ushort_t ldsCg[64*128];
  __shared__ ushort_t ldsCu[64*128];
  __shared__ ushort_t ldsRd[128*64];
  __shared__ ushort_t ldsH [128*64];

  const int tid = threadIdx.x;
  const int by = blockIdx.y, bz = blockIdx.z;
  const bool shm = (by == NEXP);
  if (bz >= (shm ? 4 : 2)) return;
  const int nrows = shm ? T_TOK : cntA[by];
  const int s0 = blockIdx.x * 128;
  if (s0 >= nrows) return;
  const int base = shm ? 0 : offA[by];
  const int Ifull = shm ? ISH : IR;
  const ushort_t* pCg = shm ? sCg : Cg + (size_t)by*IR*128;
  const ushort_t* pCu = shm ? sCu : Cu + (size_t)by*IR*128;
  const ushort_t* pRd = shm ? sRd : Rd;
  const ushort_t* srcT1 = shm ? t1S : t1R;
  const ushort_t* srcT2 = shm ? t2S : t2R;
  const int rowbase = shm ? 0 : base;

  const int lane = tid & 63, ln = lane & 15, q = lane >> 4;
  const int w = tid >> 6;
  const int it0 = bz * MTILES;

  // token fragments (B operand) -> registers
  short8 t1f[2][4], t2f[2][4];
  #pragma unroll
  for (int nj = 0; nj < 2; ++nj) {
    int rl = s0 + w*32 + nj*16 + ln; if (rl > nrows-1) rl = nrows-1;
    size_t gr = (size_t)(rowbase + rl)*128;
    #pragma unroll
    for (int c = 0; c < 4; ++c) {
      t1f[nj][c] = *(const short8*)(srcT1 + gr + c*32 + q*8);
      t2f[nj][c] = *(const short8*)(srcT2 + gr + c*32 + q*8);
    }
  }

  load_64x128_swz(pCg + (size_t)it0*64*128, 128, ldsCg, tid);
  load_64x128_swz(pCu + (size_t)it0*64*128, 128, ldsCu, tid);

  f32x4 rdacc[8][2];
  #pragma unroll
  for (int mi = 0; mi < 8; ++mi)
    #pragma unroll
    for (int nj = 0; nj < 2; ++nj) rdacc[mi][nj] = (f32x4){0.f,0.f,0.f,0.f};

  __syncthreads();   // Cg/Cu tile 0 landed

  for (int it = 0; it < MTILES; ++it) {
    const int i0 = (it0 + it) * 64;
    load_128x64_swz(pRd + i0, Ifull, ldsRd, tid);   // Rd(it) in flight during gu
    #pragma unroll
    for (int half = 0; half < 2; ++half) {
      f32x4 g[2][2], u[2][2];
      #pragma unroll
      for (int im = 0; im < 2; ++im)
        #pragma unroll
        for (int nj = 0; nj < 2; ++nj) { g[im][nj] = (f32x4){0.f,0.f,0.f,0.f}; u[im][nj] = (f32x4){0.f,0.f,0.f,0.f}; }
      #pragma unroll
      for (int c = 0; c < 4; ++c) {
        short8 ag[2], au[2];
        #pragma unroll
        for (int im = 0; im < 2; ++im) {
          int rr = (half*2+im)*16 + ln;
          int off = rr*128 + (((c*4+q) ^ ln) << 3);
          ag[im] = *(const short8*)(ldsCg + off);
          au[im] = *(const short8*)(ldsCu + off);
        }
        #pragma unroll
        for (int im = 0; im < 2; ++im)
          #pragma unroll
          for (int nj = 0; nj < 2; ++nj) {
            g[im][nj] = MF(ag[im], t1f[nj][c], g[im][nj]);
            u[im][nj] = MF(au[im], t2f[nj][c], u[im][nj]);
          }
      }
      #pragma unroll
      for (int im = 0; im < 2; ++im)
        #pragma unroll
        for (int nj = 0; nj < 2; ++nj) {
          f32x4 hv;
          #pragma unroll
          for (int r = 0; r < 4; ++r) {
            float gv = g[im][nj][r];
            gv = gv / (1.f + __expf(-gv));
            hv[r] = gv * u[im][nj][r];
          }
          int mi = half*2 + im;
          int tok = w*32 + nj*16 + ln;
          int c8 = 2*mi + (q>>1);
          *(ushort4*)(ldsH + tok*64 + ((c8 ^ (ln&7)) << 3) + 4*(q&1)) = pk4(hv);
        }
    }
    __syncthreads();   // h visible; Rd(it) landed
    if (it+1 < MTILES) {
      load_64x128_swz(pCg + (size_t)(i0+64)*128, 128, ldsCg, tid);
      load_64x128_swz(pCu + (size_t)(i0+64)*128, 128, ldsCu, tid);
    }
    #pragma unroll
    for (int c2 = 0; c2 < 2; ++c2) {
      short8 bh[2];
      #pragma unroll
      for (int nj = 0; nj < 2; ++nj) {
        int tok = w*32 + nj*16 + ln;
        bh[nj] = *(const short8*)(ldsH + tok*64 + (((c2*4+q) ^ (ln&7)) << 3));
      }
      #pragma unroll
      for (int mi = 0; mi < 8; ++mi) {
        int rr = mi*16 + ln;
        short8 ar = *(const short8*)(ldsRd + rr*64 + (((c2*4+q) ^ (ln&7)) << 3));
        #pragma unroll
        for (int nj = 0; nj < 2; ++nj) rdacc[mi][nj] = MF(ar, bh[nj], rdacc[mi][nj]);
      }
    }
    __syncthreads();   // Cg/Cu(it+1) landed; ldsH/ldsRd reads done
  }

  #pragma unroll
  for (int nj = 0; nj < 2; ++nj) {
    int tok = w*32 + nj*16 + ln;
    int gs = s0 + tok;
    if (gs < nrows) {
      float* dstrow = shm ? (rdSp + ((size_t)bz*T_TOK + gs)*128)
                          : (rdRp + ((size_t)bz*NPAIR + base + gs)*128);
      #pragma unroll
      for (int mi = 0; mi < 8; ++mi)
        *(f32x4*)(dstrow + mi*16 + q*4) = rdacc[mi][nj];
    }
  }
}

// ---------------------------------------------------------------- ypart
// grid (32, 33, 2). Prologue: rd = sum(partials) -> t3 = rd@Ud^T (LDS).
// Loop: y = w * (t3 @ Cd^T) -> plain ushort4 stores to ybuf (no atomics).
__global__ __launch_bounds__(256) void ypart_kernel(
    const float* __restrict__ rdRp, const float* __restrict__ rdSp,
    const ushort_t* __restrict__ Ud, const ushort_t* __restrict__ Cd,
    const ushort_t* __restrict__ sUd, const ushort_t* __restrict__ sCd,
    const int* __restrict__ offA, const int* __restrict__ cntA,
    const float* __restrict__ list_w,
    ushort_t* __restrict__ ybufR, ushort_t* __restrict__ ybufS)
{
  __shared__ ushort_t smem[32768];   // 64 KB
  ushort_t* ldsA  = smem;            // 64x128
  ushort_t* ldsW  = smem + 8192;     // 64x128
  ushort_t* ldsT3 = smem + 16384;    // 128x128
  ushort_t* cd0   = smem;
  ushort_t* cd1   = smem + 8192;

  const int tid = threadIdx.x;
  const int by = blockIdx.y, bz = blockIdx.z;
  const bool shm = (by == NEXP);
  const int nrows = shm ? T_TOK : cntA[by];
  const int s0 = blockIdx.x * 128;
  if (s0 >= nrows) return;
  const int base = shm ? 0 : offA[by];
  const ushort_t* pUd = shm ? sUd : Ud + (size_t)by*128*128;
  const ushort_t* pCd = shm ? sCd : Cd + (size_t)by*HD*128;

  const int lane = tid & 63, ln = lane & 15, q = lane >> 4;
  const int w = tid >> 6;

  // -------- prologue: t3 --------
  for (int th = 0; th < 2; ++th) {
    for (int li = tid; li < 1024; li += 256) {
      int r = li >> 4, g8 = li & 15;
      int row = s0 + th*64 + r; if (row > nrows-1) row = nrows-1;
      float v[8];
      if (!shm) {
        const float* p0 = rdRp + ((size_t)base + row)*128 + g8*8;
        const float* p1 = rdRp + ((size_t)NPAIR + base + row)*128 + g8*8;
        #pragma unroll
        for (int e = 0; e < 8; ++e) v[e] = p0[e] + p1[e];
      } else {
        #pragma unroll
        for (int e = 0; e < 8; ++e) v[e] = 0.f;
        #pragma unroll
        for (int z = 0; z < 4; ++z) {
          const float* p = rdSp + ((size_t)z*T_TOK + row)*128 + g8*8;
          #pragma unroll
          for (int e = 0; e < 8; ++e) v[e] += p[e];
        }
      }
      ushort_t o[8];
      #pragma unroll
      for (int e = 0; e < 8; ++e) o[e] = f2b(v[e]);
      *(short8*)(ldsA + r*128 + ((g8 ^ (r&15)) << 3)) = *(short8*)o;
    }
    __syncthreads();
    for (int uh = 0; uh < 2; ++uh) {
      for (int li = tid; li < 1024; li += 256) {
        int r = li >> 4, g8 = li & 15;
        *(short8*)(ldsW + r*128 + ((g8 ^ (r&15)) << 3)) =
            *(const short8*)(pUd + (size_t)(uh*64 + r)*128 + g8*8);
      }
      __syncthreads();
      f32x4 acc[4];
      #pragma unroll
      for (int mi = 0; mi < 4; ++mi) acc[mi] = (f32x4){0.f,0.f,0.f,0.f};
      #pragma unroll
      for (int c = 0; c < 4; ++c) {
        short8 b = *(const short8*)(ldsA + (w*16+ln)*128 + (((c*4+q) ^ ln) << 3));
        #pragma unroll
        for (int mi = 0; mi < 4; ++mi) {
          short8 a = *(const short8*)(ldsW + (mi*16+ln)*128 + (((c*4+q) ^ ln) << 3));
          acc[mi] = MF(a, b, acc[mi]);
        }
      }
      int tok = th*64 + w*16 + ln;
      #pragma unroll
      for (int mi = 0; mi < 4; ++mi) {
        int row0 = uh*64 + mi*16 + q*4;
        *(ushort4*)(ldsT3 + tok*128 + ((((row0>>3)) ^ (tok&15)) << 3) + (row0&7)) = pk4(acc[mi]);
      }
      __syncthreads();
    }
  }

  // t3 fragments + weights
  short8 t3f[2][4];
  float wv[2];
  #pragma unroll
  for (int nj = 0; nj < 2; ++nj) {
    int tok = w*32 + nj*16 + ln;
    #pragma unroll
    for (int c = 0; c < 4; ++c)
      t3f[nj][c] = *(const short8*)(ldsT3 + tok*128 + (((c*4+q) ^ ln) << 3));
    int gs = s0 + tok; if (gs > nrows-1) gs = nrows-1;
    wv[nj] = shm ? 1.f : list_w[base + gs];
  }

  // -------- Cd loop --------
  load_64x128_swz(pCd + (size_t)(bz*16)*64*128, 128, cd0, tid);
  for (int tt = 0; tt < 16; ++tt) {
    __syncthreads();
    ushort_t* cur = (tt & 1) ? cd1 : cd0;
    ushort_t* nxt = (tt & 1) ? cd0 : cd1;
    if (tt+1 < 16)
      load_64x128_swz(pCd + (size_t)(bz*16 + tt + 1)*64*128, 128, nxt, tid);
    f32x4 y[4][2];
    #pragma unroll
    for (int mi = 0; mi < 4; ++mi)
      #pragma unroll
      for (int nj = 0; nj < 2; ++nj) y[mi][nj] = (f32x4){0.f,0.f,0.f,0.f};
    #pragma unroll
    for (int c = 0; c < 4; ++c) {
      #pragma unroll
      for (int mi = 0; mi < 4; ++mi) {
        int rr = mi*16 + ln;
        short8 a = *(const short8*)(cur + rr*128 + (((c*4+q) ^ ln) << 3));
        #pragma unroll
        for (int nj = 0; nj < 2; ++nj) y[mi][nj] = MF(a, t3f[nj][c], y[mi][nj]);
      }
    }
    #pragma unroll
    for (int nj = 0; nj < 2; ++nj) {
      int tok = w*32 + nj*16 + ln;
      int gs = s0 + tok;
      if (gs < nrows) {
        ushort_t* yrow = shm ? (ybufS + (size_t)gs*HD) : (ybufR + (size_t)(base+gs)*HD);
        #pragma unroll
        for (int mi = 0; mi < 4; ++mi) {
          int h0 = (bz*16 + tt)*64 + mi*16 + q*4;
          f32x4 vy = y[mi][nj];
          #pragma unroll
          for (int r = 0; r < 4; ++r) vy[r] *= wv[nj];
          *(ushort4*)(yrow + h0) = pk4(vy);
        }
      }
    }
  }
}

// ---------------------------------------------------------------- reduce
__global__ __launch_bounds__(256) void reduce_kernel(
    const ushort_t* __restrict__ ybufR, const ushort_t* __restrict__ ybufS,
    const int* __restrict__ slot_of, float* __restrict__ out)
{
  const int t = blockIdx.x;
  const int h0 = threadIdx.x * 8;
  int s0i = slot_of[t*4+0], s1i = slot_of[t*4+1], s2i = slot_of[t*4+2], s3i = slot_of[t*4+3];
  float acc[8];
  {
    short8 v = *(const short8*)(ybufS + (size_t)t*HD + h0);
    #pragma unroll
    for (int e = 0; e < 8; ++e) acc[e] = b2f((ushort_t)v[e]);
  }
  const int ss[4] = {s0i, s1i, s2i, s3i};
  #pragma unroll
  for (int k = 0; k < 4; ++k) {
    short8 v = *(const short8*)(ybufR + (size_t)ss[k]*HD + h0);
    #pragma unroll
    for (int e = 0; e < 8; ++e) acc[e] += b2f((ushort_t)v[e]);
  }
  float4 o0 = {acc[0], acc[1], acc[2], acc[3]};
  float4 o1 = {acc[4], acc[5], acc[6], acc[7]};
  *(float4*)(out + (size_t)t*HD + h0)     = o0;
  *(float4*)(out + (size_t)t*HD + h0 + 4) = o1;
}

// ---------------------------------------------------------------- launch
extern "C" void kernel_launch(void* const* d_in, const int* in_sizes, int n_in,
                              void* d_out, int out_size, void* d_ws, size_t ws_size,
                              hipStream_t stream) {
  const float* x    = (const float*)d_in[0];
  const float* gw   = (const float*)d_in[1];
  const float* Rg   = (const float*)d_in[2];
  const float* Ru   = (const float*)d_in[3];
  const float* Rd   = (const float*)d_in[4];
  const float* Ug   = (const float*)d_in[5];
  const float* Cg   = (const float*)d_in[6];
  const float* Uu   = (const float*)d_in[7];
  const float* Cu   = (const float*)d_in[8];
  const float* Ud   = (const float*)d_in[9];
  const float* Cd   = (const float*)d_in[10];
  const float* sRg  = (const float*)d_in[11];
  const float* sUg  = (const float*)d_in[12];
  const float* sCg  = (const float*)d_in[13];
  const float* sRu  = (const float*)d_in[14];
  const float* sUu  = (const float*)d_in[15];
  const float* sCu  = (const float*)d_in[16];
  const float* sRd  = (const float*)d_in[17];
  const float* sUd  = (const float*)d_in[18];
  const float* sCd  = (const float*)d_in[19];
  float* out = (float*)d_out;

  char* w = (char*)d_ws;
  auto alloc = [&](size_t bytes) -> void* {
    void* p = (void*)w; w += (bytes + 255) & ~(size_t)255; return p;
  };
  int*   cnt      = (int*)  alloc(NEXP*sizeof(int));
  int*   offA     = (int*)  alloc((NEXP+1)*sizeof(int));
  int*   fill     = (int*)  alloc(NEXP*sizeof(int));
  int*   topk_idx = (int*)  alloc((size_t)T_TOK*4*sizeof(int));
  float* topk_w   = (float*)alloc((size_t)T_TOK*4*sizeof(float));
  int*   list_tok = (int*)  alloc((size_t)NPAIR*sizeof(int));
  float* list_w   = (float*)alloc((size_t)NPAIR*sizeof(float));
  int*   slot_of  = (int*)  alloc((size_t)NPAIR*sizeof(int));
  // weights (bf16), live whole launch
  ushort_t* Rgb  = (ushort_t*)alloc((size_t)128*HD*2);
  ushort_t* Rub  = (ushort_t*)alloc((size_t)128*HD*2);
  ushort_t* Rdb  = (ushort_t*)alloc((size_t)128*IR*2);
  ushort_t* Ugb  = (ushort_t*)alloc((size_t)NEXP*128*128*2);
  ushort_t* Cgb  = (ushort_t*)alloc((size_t)NEXP*IR*128*2);
  ushort_t* Uub  = (ushort_t*)alloc((size_t)NEXP*128*128*2);
  ushort_t* Cub  = (ushort_t*)alloc((size_t)NEXP*IR*128*2);
  ushort_t* Udb  = (ushort_t*)alloc((size_t)NEXP*128*128*2);
  ushort_t* Cdb  = (ushort_t*)alloc((size_t)NEXP*HD*128*2);
  ushort_t* sRgb = (ushort_t*)alloc((size_t)128*HD*2);
  ushort_t* sUgb = (ushort_t*)alloc((size_t)128*128*2);
  ushort_t* sCgb = (ushort_t*)alloc((size_t)ISH*128*2);
  ushort_t* sRub = (ushort_t*)alloc((size_t)128*HD*2);
  ushort_t* sUub = (ushort_t*)alloc((size_t)128*128*2);
  ushort_t* sCub = (ushort_t*)alloc((size_t)ISH*128*2);
  ushort_t* sRdb = (ushort_t*)alloc((size_t)128*ISH*2);
  ushort_t* sUdb = (ushort_t*)alloc((size_t)128*128*2);
  ushort_t* sCdb = (ushort_t*)alloc((size_t)HD*128*2);
  // rd partials (fp32), live mid -> ypart
  float* rdRp = (float*)alloc((size_t)2*NPAIR*128*sizeof(float));
  float* rdSp = (float*)alloc((size_t)4*T_TOK*128*sizeof(float));
  // overlay region: [xb | rg ru sa su | t1R t2R t1S t2S] then reused as [ybufR | ybufS]
  char* R = (char*)alloc((size_t)(NPAIR + T_TOK)*HD*2);
  ushort_t* ybufR = (ushort_t*)R;                       // NPAIR x 2048 bf16 (67 MB)
  ushort_t* ybufS = ybufR + (size_t)NPAIR*HD;           // T x 2048 bf16 (16.8 MB)
  ushort_t* xb  = (ushort_t*)R;
  ushort_t* rg  = xb + (size_t)T_TOK*HD;
  ushort_t* ru  = rg + (size_t)T_TOK*128;
  ushort_t* sa  = ru + (size_t)T_TOK*128;
  ushort_t* su  = sa + (size_t)T_TOK*128;
  ushort_t* t1R = su + (size_t)T_TOK*128;
  ushort_t* t2R = t1R + (size_t)NPAIR*128;
  ushort_t* t1S = t2R + (size_t)NPAIR*128;
  ushort_t* t2S = t1S + (size_t)T_TOK*128;
  (void)ws_size; (void)in_sizes; (void)n_in;

  (void)hipMemsetAsync(cnt,  0, NEXP*sizeof(int), stream);
  (void)hipMemsetAsync(fill, 0, NEXP*sizeof(int), stream);

  CvtSegs cs;
  const float* ss[NSEG] = {x,Rg,Ru,Rd,Ug,Cg,Uu,Cu,Ud,Cd,sRg,sUg,sCg,sRu,sUu,sCu,sRd,sUd,sCd};
  ushort_t* dd[NSEG] = {xb,Rgb,Rub,Rdb,Ugb,Cgb,Uub,Cub,Udb,Cdb,sRgb,sUgb,sCgb,sRub,sUub,sCub,sRdb,sUdb,sCdb};
  size_t nn[NSEG] = {(size_t)T_TOK*HD,(size_t)128*HD,(size_t)128*HD,(size_t)128*IR,
                     (size_t)NEXP*128*128,(size_t)NEXP*IR*128,(size_t)NEXP*128*128,(size_t)NEXP*IR*128,
                     (size_t)NEXP*128*128,(size_t)NEXP*HD*128,(size_t)128*HD,(size_t)128*128,
                     (size_t)ISH*128,(size_t)128*HD,(size_t)128*128,(size_t)ISH*128,
                     (size_t)128*ISH,(size_t)128*128,(size_t)HD*128};
  int tot_blk = 0;
  for (int k = 0; k < NSEG; ++k) {
    cs.s[k] = ss[k]; cs.d[k] = dd[k];
    cs.n4[k] = (int)(nn[k] >> 2);
    cs.blk0[k] = tot_blk;
    tot_blk += (cs.n4[k] + 255) / 256;
  }
  cs.blk0[NSEG] = tot_blk;
  cvt_all_kernel<<<tot_blk, 256, 0, stream>>>(cs);

  gate_kernel<<<T_TOK/4, 256, 0, stream>>>(x, gw, topk_idx, topk_w, cnt);
  scan_kernel<<<1, 64, 0, stream>>>(cnt, offA);
  scatter_kernel<<<T_TOK/256, 256, 0, stream>>>(topk_idx, topk_w, offA, fill,
                                                list_tok, list_w, slot_of);
  rproj_kernel<<<dim3(T_TOK/64, 4), 256, 0, stream>>>(xb, Rgb, Rub, sRgb, sRub, rg, ru, sa, su);
  pair_proj_kernel<<<dim3(64, NEXP+1), 256, 0, stream>>>(
      rg, ru, sa, su, Ugb, Uub, sUgb, sUub, offA, cnt, list_tok, t1R, t2R, t1S, t2S);
  mid_kernel<<<dim3(32, NEXP+1, 4), 256, 0, stream>>>(
      t1R, t2R, t1S, t2S, Cgb, Cub, Rdb, sCgb, sCub, sRdb, offA, cnt, rdRp, rdSp);
  ypart_kernel<<<dim3(32, NEXP+1, 2), 256, 0, stream>>>(
      rdRp, rdSp, Udb, Cdb, sUdb, sCdb, offA, cnt, list_w, ybufR, ybufS);
  reduce_kernel<<<T_TOK, 256, 0, stream>>>(ybufR, ybufS, slot_of, out);
}